// Round 5
// baseline (78.835 us; speedup 1.0000x reference)
//
#include <hip/hip_runtime.h>

// MHAGRU, 3 kernels: [input_proj] -> [GRU scan] -> [MHA || out_proj (block-branch)].
// B=32 T=64 F=128 H=8 NH=4 HD=2 HID=32. All f32.
// d_out = [ y (B*T*HID) | attention (B*T*F*H) ]
// d_ws  = [ xp (B*T*F) | out (B*F*T*H) ]  (9 MB, fully overwritten each call)
//
// R5: occupancy-first restructure. K1 one-output-per-thread (16 waves/CU);
// K2 pure scan; K3 fuses MHA and out_proj as independent block ranges so they
// co-schedule in one dispatch.

namespace {
constexpr int Bb = 32, Tt = 64, Ff = 128, Hh = 8, HIDh = 32;
constexpr int G3H = 24;
constexpr float L2E = 1.44269504088896340736f;
// K3 LDS layout (floats), per 64-lane half:
constexpr int KV4 = 0;       // float4 kv? no: k  [n][t] float4 stride 65 -> 1040
constexpr int VV4 = 1040;    // v  [n][t] float4 stride 65 -> 1040
constexpr int QS  = 2080;    // q*scale [t][2n] stride 10  -> 640
constexpr int CS  = 2720;    // ctx     [t][2n] stride 10  -> 640
constexpr int HALF = 3360;   // floats per half; 2 halves = 26.9 KB
}

__device__ __forceinline__ float rcp_(float x) {
#if __has_builtin(__builtin_amdgcn_rcpf)
  return __builtin_amdgcn_rcpf(x);
#else
  return 1.0f / x;
#endif
}
__device__ __forceinline__ float exp2_(float x) {
#if __has_builtin(__builtin_amdgcn_exp2f)
  return __builtin_amdgcn_exp2f(x);
#else
  return exp2f(x);
#endif
}

// ---------------- K1: xp = x @ Wp^T + bp, one output per thread ----------------
// grid: (B*T/2) = 1024 blocks, 256 threads = 2 rows x 128 f. 16 waves/CU.
__global__ __launch_bounds__(256) void k_inproj(
    const float* __restrict__ x, const float* __restrict__ Wp,
    const float* __restrict__ bp, float* __restrict__ xp) {
  __shared__ float xs[2][128];
  const int r0 = blockIdx.x * 2;
  const int rr = threadIdx.x >> 7;
  const int f = threadIdx.x & 127;
  xs[rr][f] = x[(r0 + rr) * Ff + f];
  __syncthreads();
  float acc = bp[f];
  const float4* wr = (const float4*)(Wp + f * Ff);
  const float* xr = xs[rr];
#pragma unroll 8
  for (int k4 = 0; k4 < Ff / 4; ++k4) {
    float4 w = wr[k4];
    float4 xv = *(const float4*)&xr[k4 * 4];
    acc = fmaf(xv.x, w.x, acc);
    acc = fmaf(xv.y, w.y, acc);
    acc = fmaf(xv.z, w.z, acc);
    acc = fmaf(xv.w, w.w, acc);
  }
  xp[(r0 + rr) * Ff + f] = acc;
}

// ---------------- K2: per-feature GRU scan over T ----------------
// grid: B*(F/8) = 512 blocks, 64 threads; lane = (g=f_local, j=hidden idx).
__global__ __launch_bounds__(64) void k_gru(
    const float* __restrict__ xp, const float* __restrict__ W_ih,
    const float* __restrict__ b_ih, const float* __restrict__ W_hh,
    const float* __restrict__ b_hh, float* __restrict__ outp) {
  __shared__ float xs[8][65];   // [f_local][t]
  const int tid = threadIdx.x;
  const int blk = blockIdx.x;
  const int b = blk >> 4;
  const int f0 = (blk & 15) * 8;
  // stage xp[b, :, f0..f0+7]
  for (int i = tid; i < Tt * 8; i += 64)
    xs[i & 7][i >> 3] = xp[(b * Tt + (i >> 3)) * Ff + f0 + (i & 7)];
  const int g = tid >> 3, j = tid & 7;
  const int f = f0 + g;
  const float* wb = W_hh + (f * G3H + j) * Hh;
  const float nL = -L2E, S2 = 2.0f * L2E;
  float w0s[8], w1s[8], w2s[8];
#pragma unroll
  for (int h = 0; h < 8; ++h) {
    w0s[h] = wb[h] * nL;
    w1s[h] = wb[64 + h] * nL;
    w2s[h] = wb[128 + h] * S2;
  }
  const float wi0s = W_ih[f * G3H + j] * nL;
  const float wi1s = W_ih[f * G3H + 8 + j] * nL;
  const float wi2s = W_ih[f * G3H + 16 + j] * S2;
  const float bias_r = (b_ih[f * G3H + j] + b_hh[f * G3H + j]) * nL;
  const float bias_z = (b_ih[f * G3H + 8 + j] + b_hh[f * G3H + 8 + j]) * nL;
  const float bi2s = b_ih[f * G3H + 16 + j] * S2;
  const float bh2s = b_hh[f * G3H + 16 + j] * S2;
  float hall[8];
#pragma unroll
  for (int h = 0; h < 8; ++h) hall[h] = 0.f;
  const int base = tid & 56;
  float* outb = outp + ((b * Ff + f) * Tt) * Hh + j;
  const float* xps = &xs[g][0];
  __syncthreads();
  for (int t = 0; t < Tt; ++t) {
    float xt = xps[t];
    float a0 = bias_r, a1 = bias_z, a2 = bh2s;
#pragma unroll
    for (int h = 0; h < 8; ++h) {
      a0 = fmaf(hall[h], w0s[h], a0);
      a1 = fmaf(hall[h], w1s[h], a1);
      a2 = fmaf(hall[h], w2s[h], a2);
    }
    float r = rcp_(1.0f + exp2_(fmaf(xt, wi0s, a0)));
    float z = rcp_(1.0f + exp2_(fmaf(xt, wi1s, a1)));
    float narg = fmaf(r, a2, fmaf(xt, wi2s, bi2s));
    float n = fmaf(-2.0f, rcp_(exp2_(narg) + 1.0f), 1.0f);  // tanh
    float hn = fmaf(z, hall[j] - n, n);
    outb[t * Hh] = hn;
#pragma unroll
    for (int h = 0; h < 8; ++h) hall[h] = __shfl(hn, base + h, 64);
  }
}

// ---------------- K3: MHA (blocks 0..2047, 2 pairs each) || out_proj (2048..2303) ----
__global__ __launch_bounds__(128) void k_mha_outproj(
    const float* __restrict__ outp, const float* __restrict__ in_w,
    const float* __restrict__ in_b, const float* __restrict__ ow,
    const float* __restrict__ ob, const float* __restrict__ Wout,
    const float* __restrict__ bout, float* __restrict__ attn,
    float* __restrict__ y) {
  __shared__ float smem[2 * HALF];
  const int tid = threadIdx.x;
  if (blockIdx.x < 2048) {
    // ===== MHA: half-wave = one (b,f) pair =====
    const int pair = blockIdx.x * 2 + (tid >> 6);
    const int b = pair >> 7, f = pair & 127;
    const int t = tid & 63;
    float* sm = &smem[(tid >> 6) * HALF];
    // C1: qkv projection, lane = t
    const float4* src = (const float4*)(outp + pair * (Tt * Hh));
    float4 r0 = src[t * 2], r1 = src[t * 2 + 1];
    float sq[8] = {r0.x, r0.y, r0.z, r0.w, r1.x, r1.y, r1.z, r1.w};
    constexpr float SCL = 0.70710678118654752f * L2E;
    float qv[8], ka[8], va[8];
#pragma unroll
    for (int jj = 0; jj < 8; ++jj) {
      float aq = in_b[jj], ak = in_b[8 + jj], av = in_b[16 + jj];
#pragma unroll
      for (int h = 0; h < 8; ++h) {
        aq = fmaf(sq[h], in_w[jj * 8 + h], aq);
        ak = fmaf(sq[h], in_w[(8 + jj) * 8 + h], ak);
        av = fmaf(sq[h], in_w[(16 + jj) * 8 + h], av);
      }
      qv[jj] = aq * SCL; ka[jj] = ak; va[jj] = av;
    }
#pragma unroll
    for (int n = 0; n < 4; ++n) {
      *(float2*)&sm[QS + t * 10 + 2 * n] = make_float2(qv[2 * n], qv[2 * n + 1]);
      *(float4*)&sm[KV4 + (n * 65 + t) * 4] = make_float4(ka[2 * n], ka[2 * n + 1], 0.f, 0.f);
      *(float4*)&sm[VV4 + (n * 65 + t) * 4] = make_float4(va[2 * n], va[2 * n + 1], 0.f, 0.f);
    }
    __syncthreads();
    // C2: lane = (qq, n); 4 q-rows, one head; kv broadcast within 16-lane groups
    const int n = t & 3, qq = t >> 2;
    float q0[4], q1[4];
#pragma unroll
    for (int i = 0; i < 4; ++i) {
      float2 qp = *(const float2*)&sm[QS + (qq + 16 * i) * 10 + 2 * n];
      q0[i] = qp.x; q1[i] = qp.y;
    }
    float ps[4], c0[4], c1[4];
#pragma unroll
    for (int i = 0; i < 4; ++i) { ps[i] = 0.f; c0[i] = 0.f; c1[i] = 0.f; }
#pragma unroll 4
    for (int kt = 0; kt < Tt; ++kt) {
      float4 kf = *(const float4*)&sm[KV4 + (n * 65 + kt) * 4];
      float4 vf = *(const float4*)&sm[VV4 + (n * 65 + kt) * 4];
#pragma unroll
      for (int i = 0; i < 4; ++i) {
        float s = fmaf(q0[i], kf.x, q1[i] * kf.y);
        float p = exp2_(s);
        ps[i] += p;
        c0[i] = fmaf(p, vf.x, c0[i]);
        c1[i] = fmaf(p, vf.y, c1[i]);
      }
    }
#pragma unroll
    for (int i = 0; i < 4; ++i) {
      float inv = rcp_(ps[i]);
      *(float2*)&sm[CS + (qq + 16 * i) * 10 + 2 * n] =
          make_float2(c0[i] * inv, c1[i] * inv);
    }
    __syncthreads();
    // C3: out_proj cols {2n,2n+1} for rows qq+16i
    const float4* owp = (const float4*)(ow + n * 16);
    float4 wv0 = owp[0], wv1 = owp[1], wv2 = owp[2], wv3 = owp[3];
    const float ob0 = ob[2 * n], ob1 = ob[2 * n + 1];
#pragma unroll
    for (int i = 0; i < 4; ++i) {
      int row = qq + 16 * i;
      float2 cp0 = *(const float2*)&sm[CS + row * 10 + 0];
      float2 cp1 = *(const float2*)&sm[CS + row * 10 + 2];
      float2 cp2 = *(const float2*)&sm[CS + row * 10 + 4];
      float2 cp3 = *(const float2*)&sm[CS + row * 10 + 6];
      float o0 = ob0, o1 = ob1;
      o0 = fmaf(cp0.x, wv0.x, o0); o0 = fmaf(cp0.y, wv0.y, o0);
      o0 = fmaf(cp1.x, wv0.z, o0); o0 = fmaf(cp1.y, wv0.w, o0);
      o0 = fmaf(cp2.x, wv1.x, o0); o0 = fmaf(cp2.y, wv1.y, o0);
      o0 = fmaf(cp3.x, wv1.z, o0); o0 = fmaf(cp3.y, wv1.w, o0);
      o1 = fmaf(cp0.x, wv2.x, o1); o1 = fmaf(cp0.y, wv2.y, o1);
      o1 = fmaf(cp1.x, wv2.z, o1); o1 = fmaf(cp1.y, wv2.w, o1);
      o1 = fmaf(cp2.x, wv3.x, o1); o1 = fmaf(cp2.y, wv3.y, o1);
      o1 = fmaf(cp3.x, wv3.z, o1); o1 = fmaf(cp3.y, wv3.w, o1);
      *(float2*)&attn[((b * Tt + row) * Ff + f) * Hh + 2 * n] = make_float2(o0, o1);
    }
  } else {
    // ===== out_proj: y = out.reshape(B,T,F*H) @ Wout^T + bout =====
    constexpr int TT = 8;
    const int blk = blockIdx.x - 2048;
    const int b = blk >> 3;
    const int t0 = (blk & 7) * TT;
    const int oq = tid >> 4;
    const int fc = tid & 15;
    float acc[TT][4];
#pragma unroll
    for (int tt = 0; tt < TT; ++tt)
#pragma unroll
      for (int od = 0; od < 4; ++od) acc[tt][od] = 0.f;
#pragma unroll
    for (int ff = 0; ff < 8; ++ff) {
      int f = fc * 8 + ff;
      const float4* rb = (const float4*)(outp + ((b * Ff + f) * Tt + t0) * Hh);
      float4 rv[16];
#pragma unroll
      for (int i = 0; i < 16; ++i) rv[i] = rb[i];
#pragma unroll
      for (int od = 0; od < 4; ++od) {
        int o = oq * 4 + od;
        const float4* wbp = (const float4*)(Wout + o * (Ff * Hh) + f * Hh);
        float4 wa = wbp[0], wc = wbp[1];
#pragma unroll
        for (int tt = 0; tt < TT; ++tt) {
          float4 ra = rv[tt * 2], rc = rv[tt * 2 + 1];
          float s = acc[tt][od];
          s = fmaf(ra.x, wa.x, s); s = fmaf(ra.y, wa.y, s);
          s = fmaf(ra.z, wa.z, s); s = fmaf(ra.w, wa.w, s);
          s = fmaf(rc.x, wc.x, s); s = fmaf(rc.y, wc.y, s);
          s = fmaf(rc.z, wc.z, s); s = fmaf(rc.w, wc.w, s);
          acc[tt][od] = s;
        }
      }
    }
#pragma unroll
    for (int tt = 0; tt < TT; ++tt)
#pragma unroll
      for (int od = 0; od < 4; ++od) {
        float v = acc[tt][od];
        v += __shfl_xor(v, 1, 16);
        v += __shfl_xor(v, 2, 16);
        v += __shfl_xor(v, 4, 16);
        v += __shfl_xor(v, 8, 16);
        acc[tt][od] = v;
      }
#pragma unroll
    for (int tt = 0; tt < TT; ++tt) {
      if (fc == tt) {
#pragma unroll
        for (int od = 0; od < 4; ++od) {
          int o = oq * 4 + od;
          y[(b * Tt + t0 + tt) * HIDh + o] = acc[tt][od] + bout[o];
        }
      }
    }
  }
}

extern "C" void kernel_launch(void* const* d_in, const int* in_sizes, int n_in,
                              void* d_out, int out_size, void* d_ws, size_t ws_size,
                              hipStream_t stream) {
  (void)in_sizes; (void)n_in; (void)out_size; (void)ws_size;
  const float* x    = (const float*)d_in[0];
  const float* Wp   = (const float*)d_in[1];
  const float* bp   = (const float*)d_in[2];
  const float* W_ih = (const float*)d_in[3];
  const float* b_ih = (const float*)d_in[4];
  const float* W_hh = (const float*)d_in[5];
  const float* b_hh = (const float*)d_in[6];
  const float* in_w = (const float*)d_in[7];
  const float* in_b = (const float*)d_in[8];
  const float* ow   = (const float*)d_in[9];
  const float* ob   = (const float*)d_in[10];
  const float* Wout = (const float*)d_in[11];
  const float* bout = (const float*)d_in[12];

  float* y    = (float*)d_out;
  float* attn = (float*)d_out + Bb * Tt * HIDh;
  float* xp   = (float*)d_ws;                   // B*T*F
  float* outp = (float*)d_ws + Bb * Tt * Ff;    // B*F*T*H

  hipLaunchKernelGGL(k_inproj, dim3(Bb * Tt / 2), dim3(256), 0, stream, x, Wp, bp, xp);
  hipLaunchKernelGGL(k_gru, dim3(Bb * (Ff / 8)), dim3(64), 0, stream,
                     xp, W_ih, b_ih, W_hh, b_hh, outp);
  hipLaunchKernelGGL(k_mha_outproj, dim3(2304), dim3(128), 0, stream,
                     outp, in_w, in_b, ow, ob, Wout, bout, attn, y);
}

// Round 6
// 67.844 us; speedup vs baseline: 1.1620x; 1.1620x over previous
//
#include <hip/hip_runtime.h>

// MHAGRU, 2 kernels: [input_proj + GRU scan] -> [MHA (wave-per-pair) || out_proj].
// B=32 T=64 F=128 H=8 NH=4 HD=2 HID=32. All f32.
// d_out = [ y (B*T*HID) | attention (B*T*F*H) ]
// d_ws  = [ out (B*F*T*H) ]  (8 MB, fully overwritten each call)
//
// R6: two launches only (gap cost ~5-8us each). MHA redesigned: one wave per
// (b,f) pair, barrier-free (per-wave LDS + lgkmcnt waits), k/v component-split
// float4 chunks (stride-68, conflict-free broadcast) -> 4 ds_read_b128 + 96 VALU
// per 4-kt chunk with 16 independent exp2 chains.

namespace {
constexpr int Bb = 32, Tt = 64, Ff = 128, Hh = 8, HIDh = 32;
constexpr int G3H = 24;
constexpr float L2E = 1.44269504088896340736f;
// k_gruproj LDS (floats):
constexpr int XS_STRIDE = 130;
constexpr int XP_OFF = Tt * XS_STRIDE;     // 8320
constexpr int SMEM_AB = XP_OFF + 8 * 65;   // 8840 floats = 35.4 KB
// k_mha per-wave LDS region (floats): kk0|kk1|vv0|vv1 ([4][68] each) + qs/cs [64][10]
constexpr int KK0 = 0, KK1 = 272, VV0 = 544, VV1 = 816, QS = 1088;
constexpr int WREG = 1728;                 // floats per wave; x4 waves = 27648 B
}

__device__ __forceinline__ float rcp_(float x) {
#if __has_builtin(__builtin_amdgcn_rcpf)
  return __builtin_amdgcn_rcpf(x);
#else
  return 1.0f / x;
#endif
}
__device__ __forceinline__ float exp2_(float x) {
#if __has_builtin(__builtin_amdgcn_exp2f)
  return __builtin_amdgcn_exp2f(x);
#else
  return exp2f(x);
#endif
}

// ---------------- K1: input_proj + per-feature GRU (R4's proven kernel) ----------------
// grid: B*(F/8) = 512 blocks, 256 threads. Waves 1-3 retire after phase A.
__global__ __launch_bounds__(256) void k_gruproj(
    const float* __restrict__ x, const float* __restrict__ Wp, const float* __restrict__ bp,
    const float* __restrict__ W_ih, const float* __restrict__ b_ih,
    const float* __restrict__ W_hh, const float* __restrict__ b_hh,
    float* __restrict__ outp) {
  __shared__ float smem[SMEM_AB];
  const int tid = threadIdx.x;
  const int blk = blockIdx.x;
  const int b = blk >> 4;
  const int f0 = (blk & 15) * 8;
  const int lane = tid & 63;
  const int w = tid >> 6;

  // phase A: stage x[b] (64x128), compute xp for this block's 8 f's
  {
    const float2* xb = (const float2*)(x + b * Tt * Ff);
    for (int i = tid; i < Tt * Ff / 2; i += 256) {
      int row = i >> 6, col2 = i & 63;
      *(float2*)&smem[row * XS_STRIDE + col2 * 2] = xb[i];
    }
  }
  __syncthreads();
  {
    const int t = lane;
    const int fA = f0 + w, fB = f0 + w + 4;  // wave-uniform -> scalar Wp loads
    float acc0 = bp[fA], acc1 = bp[fB];
    const float* wA = Wp + fA * Ff;
    const float* wB = Wp + fB * Ff;
    const float* xr = &smem[t * XS_STRIDE];
#pragma unroll 8
    for (int k = 0; k < Ff; k += 2) {
      float2 xv = *(const float2*)&xr[k];
      acc0 = fmaf(xv.x, wA[k], acc0); acc0 = fmaf(xv.y, wA[k + 1], acc0);
      acc1 = fmaf(xv.x, wB[k], acc1); acc1 = fmaf(xv.y, wB[k + 1], acc1);
    }
    smem[XP_OFF + w * 65 + t] = acc0;
    smem[XP_OFF + (w + 4) * 65 + t] = acc1;
  }
  __syncthreads();
  if (tid >= 64) return;   // free 3/4 of the block's wave slots

  // phase B: GRU scan, lane = (g=f_local, j=hidden). exp2/rcp form.
  {
    const int g = tid >> 3, j = tid & 7;
    const int f = f0 + g;
    const float* wb = W_hh + (f * G3H + j) * Hh;
    const float nL = -L2E, S2 = 2.0f * L2E;
    float w0s[8], w1s[8], w2s[8];
#pragma unroll
    for (int h = 0; h < 8; ++h) {
      w0s[h] = wb[h] * nL;
      w1s[h] = wb[64 + h] * nL;
      w2s[h] = wb[128 + h] * S2;
    }
    const float wi0s = W_ih[f * G3H + j] * nL;
    const float wi1s = W_ih[f * G3H + 8 + j] * nL;
    const float wi2s = W_ih[f * G3H + 16 + j] * S2;
    const float bias_r = (b_ih[f * G3H + j] + b_hh[f * G3H + j]) * nL;
    const float bias_z = (b_ih[f * G3H + 8 + j] + b_hh[f * G3H + 8 + j]) * nL;
    const float bi2s = b_ih[f * G3H + 16 + j] * S2;
    const float bh2s = b_hh[f * G3H + 16 + j] * S2;
    float hall[8];
#pragma unroll
    for (int h = 0; h < 8; ++h) hall[h] = 0.f;
    const int base = tid & 56;
    float* outb = outp + ((b * Ff + f) * Tt) * Hh + j;
    const float* xps = &smem[XP_OFF + g * 65];
    for (int t = 0; t < Tt; ++t) {
      float xt = xps[t];
      float a0 = bias_r, a1 = bias_z, a2 = bh2s;
#pragma unroll
      for (int h = 0; h < 8; ++h) {
        a0 = fmaf(hall[h], w0s[h], a0);
        a1 = fmaf(hall[h], w1s[h], a1);
        a2 = fmaf(hall[h], w2s[h], a2);
      }
      float r = rcp_(1.0f + exp2_(fmaf(xt, wi0s, a0)));
      float z = rcp_(1.0f + exp2_(fmaf(xt, wi1s, a1)));
      float narg = fmaf(r, a2, fmaf(xt, wi2s, bi2s));
      float n = fmaf(-2.0f, rcp_(exp2_(narg) + 1.0f), 1.0f);  // tanh
      float hn = fmaf(z, hall[j] - n, n);
      outb[t * Hh] = hn;
#pragma unroll
      for (int h = 0; h < 8; ++h) hall[h] = __shfl(hn, base + h, 64);
    }
  }
}

// per-component softmax+PV step (static indexing throughout)
#define MHA_STEP(K0C, K1C, V0C, V1C)                         \
  {                                                          \
    _Pragma("unroll") for (int i = 0; i < 4; ++i) {          \
      float s = fmaf(q0[i], K0C, q1[i] * K1C);               \
      float p = exp2_(s);                                    \
      ps[i] += p;                                            \
      c0[i] = fmaf(p, V0C, c0[i]);                           \
      c1[i] = fmaf(p, V1C, c1[i]);                           \
    }                                                        \
  }

// ---------------- K2: MHA (blocks 0..1023; wave = (b,f) pair) || out_proj ----------------
__global__ __launch_bounds__(256) void k_mha_outproj(
    const float* __restrict__ outp, const float* __restrict__ in_w,
    const float* __restrict__ in_b, const float* __restrict__ ow,
    const float* __restrict__ ob, const float* __restrict__ Wout,
    const float* __restrict__ bout, float* __restrict__ attn,
    float* __restrict__ y) {
  __shared__ float smem[4 * WREG];
  const int tid = threadIdx.x;
  if (blockIdx.x < 1024) {
    // ===== MHA: one 64-lane wave per (b,f) pair; no __syncthreads anywhere =====
    const int wv = tid >> 6;
    const int t = tid & 63;
    const int pair = blockIdx.x * 4 + wv;
    const int b = pair >> 7, f = pair & 127;
    float* sm = &smem[wv * WREG];

    // C1: qkv projection, lane = t
    const float4* src = (const float4*)(outp + pair * (Tt * Hh));
    float4 r0 = src[t * 2], r1 = src[t * 2 + 1];
    float sq[8] = {r0.x, r0.y, r0.z, r0.w, r1.x, r1.y, r1.z, r1.w};
    constexpr float SCL = 0.70710678118654752f * L2E;
    float qv[8], ka[8], va[8];
#pragma unroll
    for (int jj = 0; jj < 8; ++jj) {
      float aq = in_b[jj], ak = in_b[8 + jj], av = in_b[16 + jj];
#pragma unroll
      for (int h = 0; h < 8; ++h) {
        aq = fmaf(sq[h], in_w[jj * 8 + h], aq);
        ak = fmaf(sq[h], in_w[(8 + jj) * 8 + h], ak);
        av = fmaf(sq[h], in_w[(16 + jj) * 8 + h], av);
      }
      qv[jj] = aq * SCL; ka[jj] = ak; va[jj] = av;
    }
#pragma unroll
    for (int n = 0; n < 4; ++n) {
      *(float2*)&sm[QS + t * 10 + 2 * n] = make_float2(qv[2 * n], qv[2 * n + 1]);
      sm[KK0 + n * 68 + t] = ka[2 * n];        // banks (4n+t)%32: 2-way, free
      sm[KK1 + n * 68 + t] = ka[2 * n + 1];
      sm[VV0 + n * 68 + t] = va[2 * n];
      sm[VV1 + n * 68 + t] = va[2 * n + 1];
    }
    asm volatile("s_waitcnt lgkmcnt(0)" ::: "memory");  // within-wave RAW

    // C2: lane = (n = t>>4, qq = t&15); 4 q-rows x 1 head.
    const int n = t >> 4, qq = t & 15;
    float q0[4], q1[4];
#pragma unroll
    for (int i = 0; i < 4; ++i) {
      float2 qp = *(const float2*)&sm[QS + (qq + 16 * i) * 10 + 2 * n];
      q0[i] = qp.x; q1[i] = qp.y;
    }
    float ps[4], c0[4], c1[4];
#pragma unroll
    for (int i = 0; i < 4; ++i) { ps[i] = 0.f; c0[i] = 0.f; c1[i] = 0.f; }
#pragma unroll 2
    for (int kt4 = 0; kt4 < Tt; kt4 += 4) {
      // 4 x ds_read_b128; addr banks 4n+4kt4.. -> distinct per n-group, broadcast within
      float4 k0 = *(const float4*)&sm[KK0 + n * 68 + kt4];
      float4 k1 = *(const float4*)&sm[KK1 + n * 68 + kt4];
      float4 v0 = *(const float4*)&sm[VV0 + n * 68 + kt4];
      float4 v1 = *(const float4*)&sm[VV1 + n * 68 + kt4];
      MHA_STEP(k0.x, k1.x, v0.x, v1.x)
      MHA_STEP(k0.y, k1.y, v0.y, v1.y)
      MHA_STEP(k0.z, k1.z, v0.z, v1.z)
      MHA_STEP(k0.w, k1.w, v0.w, v1.w)
    }
#pragma unroll
    for (int i = 0; i < 4; ++i) {
      float inv = rcp_(ps[i]);
      // q regs consumed long ago; reuse QS region for ctx
      *(float2*)&sm[QS + (qq + 16 * i) * 10 + 2 * n] =
          make_float2(c0[i] * inv, c1[i] * inv);
    }
    asm volatile("s_waitcnt lgkmcnt(0)" ::: "memory");

    // C3: lane = t; out_proj of ctx row t
    float2 cp0 = *(const float2*)&sm[QS + t * 10 + 0];
    float2 cp1 = *(const float2*)&sm[QS + t * 10 + 2];
    float2 cp2 = *(const float2*)&sm[QS + t * 10 + 4];
    float2 cp3 = *(const float2*)&sm[QS + t * 10 + 6];
    float cx[8] = {cp0.x, cp0.y, cp1.x, cp1.y, cp2.x, cp2.y, cp3.x, cp3.y};
    float o8[8];
#pragma unroll
    for (int jj = 0; jj < 8; ++jj) {
      float a = ob[jj];
#pragma unroll
      for (int h = 0; h < 8; ++h) a = fmaf(cx[h], ow[jj * 8 + h], a);
      o8[jj] = a;
    }
    float4* dst = (float4*)(attn + ((b * Tt + t) * Ff + f) * Hh);
    dst[0] = make_float4(o8[0], o8[1], o8[2], o8[3]);
    dst[1] = make_float4(o8[4], o8[5], o8[6], o8[7]);
  } else {
    // ===== out_proj: two independent 128-thread sub-units per block =====
    constexpr int TT = 8;
    const int sub = tid >> 7, stid = tid & 127;
    const int eblk = (blockIdx.x - 1024) * 2 + sub;   // 0..255
    const int b = eblk >> 3;
    const int t0 = (eblk & 7) * TT;
    const int oq = stid >> 4;
    const int fc = stid & 15;
    float acc[TT][4];
#pragma unroll
    for (int tt = 0; tt < TT; ++tt)
#pragma unroll
      for (int od = 0; od < 4; ++od) acc[tt][od] = 0.f;
#pragma unroll
    for (int ff = 0; ff < 8; ++ff) {
      int f = fc * 8 + ff;
      const float4* rb = (const float4*)(outp + ((b * Ff + f) * Tt + t0) * Hh);
      float4 rv[16];
#pragma unroll
      for (int i = 0; i < 16; ++i) rv[i] = rb[i];
#pragma unroll
      for (int od = 0; od < 4; ++od) {
        int o = oq * 4 + od;
        const float4* wbp = (const float4*)(Wout + o * (Ff * Hh) + f * Hh);
        float4 wa = wbp[0], wc = wbp[1];
#pragma unroll
        for (int tt = 0; tt < TT; ++tt) {
          float4 ra = rv[tt * 2], rc = rv[tt * 2 + 1];
          float s = acc[tt][od];
          s = fmaf(ra.x, wa.x, s); s = fmaf(ra.y, wa.y, s);
          s = fmaf(ra.z, wa.z, s); s = fmaf(ra.w, wa.w, s);
          s = fmaf(rc.x, wc.x, s); s = fmaf(rc.y, wc.y, s);
          s = fmaf(rc.z, wc.z, s); s = fmaf(rc.w, wc.w, s);
          acc[tt][od] = s;
        }
      }
    }
#pragma unroll
    for (int tt = 0; tt < TT; ++tt)
#pragma unroll
      for (int od = 0; od < 4; ++od) {
        float v = acc[tt][od];
        v += __shfl_xor(v, 1, 16);
        v += __shfl_xor(v, 2, 16);
        v += __shfl_xor(v, 4, 16);
        v += __shfl_xor(v, 8, 16);
        acc[tt][od] = v;
      }
#pragma unroll
    for (int tt = 0; tt < TT; ++tt) {
      if (fc == tt) {
#pragma unroll
        for (int od = 0; od < 4; ++od) {
          int o = oq * 4 + od;
          y[(b * Tt + t0 + tt) * HIDh + o] = acc[tt][od] + bout[o];
        }
      }
    }
  }
}

extern "C" void kernel_launch(void* const* d_in, const int* in_sizes, int n_in,
                              void* d_out, int out_size, void* d_ws, size_t ws_size,
                              hipStream_t stream) {
  (void)in_sizes; (void)n_in; (void)out_size; (void)ws_size;
  const float* x    = (const float*)d_in[0];
  const float* Wp   = (const float*)d_in[1];
  const float* bp   = (const float*)d_in[2];
  const float* W_ih = (const float*)d_in[3];
  const float* b_ih = (const float*)d_in[4];
  const float* W_hh = (const float*)d_in[5];
  const float* b_hh = (const float*)d_in[6];
  const float* in_w = (const float*)d_in[7];
  const float* in_b = (const float*)d_in[8];
  const float* ow   = (const float*)d_in[9];
  const float* ob   = (const float*)d_in[10];
  const float* Wout = (const float*)d_in[11];
  const float* bout = (const float*)d_in[12];

  float* y    = (float*)d_out;
  float* attn = (float*)d_out + Bb * Tt * HIDh;
  float* outp = (float*)d_ws;   // B*F*T*H

  hipLaunchKernelGGL(k_gruproj, dim3(Bb * (Ff / 8)), dim3(256), 0, stream,
                     x, Wp, bp, W_ih, b_ih, W_hh, b_hh, outp);
  hipLaunchKernelGGL(k_mha_outproj, dim3(1152), dim3(256), 0, stream,
                     outp, in_w, in_b, ow, ob, Wout, bout, attn, y);
}